// Round 1
// 229.281 us; speedup vs baseline: 1.0366x; 1.0366x over previous
//
#include <hip/hip_runtime.h>

// Hopf oscillator scan.
// X_r, X_i: [bs=8, T=64, d=32, d=32, nk=32] fp32; omegas: [32,32,32].
// Outputs: (r*cos(phi), r*sin(phi)) each [8,64,32,32,32], concatenated.
// 262,144 independent chains over (bs,d,d,nk); T sequential.
//
// R5: dwordx4 streaming. R4 (depth-16 scalar pipeline) fixed MLP but issued
// 4 B/lane memory ops (256 B/wave-inst) and plateaued at 3.2 TB/s -- half the
// float4 streaming ceiling (m13: 6.3 TB/s measured with 16 B/lane). Each
// thread now owns 4 adjacent chains: every load/store is a nontemporal
// global_*_dwordx4 (1 KiB/wave-inst). Depth-8 float4 register pipeline keeps
// 16 dwordx4 loads in flight per wave (~16 MB device-wide MLP at 1024 waves).
// Trig via small-angle rotation (R3). Full unroll of T=64.

#define T_STEPS 64
#define CHV     8192          // float4-chains per batch image (32768 / 4)
#define BS      8
#define DEPTH   8             // pipeline depth in t-steps (2 x dwordx4 per step)

typedef float v4f __attribute__((ext_vector_type(4)));

__global__ __launch_bounds__(256)
void hopf_scan_kernel(const float* __restrict__ Xr,
                      const float* __restrict__ Xi,
                      const float* __restrict__ Om,
                      float* __restrict__ out)
{
    const float DT = 0.01f;
    const float SC = 20.0f;
    // sin(x) = x*(1 + u*(S1 + u*(S2 + u*(S3 + u*S4)))), u = x^2
    const float S1 = -1.6666667e-1f, S2 = 8.3333333e-3f,
                S3 = -1.9841270e-4f, S4 = 2.7557319e-6f;
    // cos(x) = 1 + u*(C1 + u*(C2 + u*(C3 + u*C4)))
    const float C1 = -0.5f, C2 = 4.1666667e-2f,
                C3 = -1.3888889e-3f, C4 = 2.4801587e-5f;

    const v4f* __restrict__ vXr = (const v4f*)Xr;
    const v4f* __restrict__ vXi = (const v4f*)Xi;
    const v4f* __restrict__ vOm = (const v4f*)Om;
    v4f* __restrict__ vout      = (v4f*)out;

    int tid = blockIdx.x * blockDim.x + threadIdx.x;   // 0 .. 65535
    int b   = tid >> 13;                               // CHV = 8192 vec-chains
    int cv  = tid & (CHV - 1);

    v4f om = vOm[cv];

    const size_t stride = CHV;                         // v4f elements per t
    size_t base = (size_t)(b * T_STEPS) * stride + cv;
    const v4f* pxr = vXr + base;
    const v4f* pxi = vXi + base;
    v4f* po0 = vout + base;
    v4f* po1 = po0 + (size_t)BS * T_STEPS * stride;

    float r[4]  = {1.f, 1.f, 1.f, 1.f};
    float co[4] = {1.f, 1.f, 1.f, 1.f};
    float si[4] = {0.f, 0.f, 0.f, 0.f};                // phi0 = 0

    // prime: loads for t = 0..DEPTH-1 (16 dwordx4 loads in flight)
    v4f xr[DEPTH], xi[DEPTH];
    #pragma unroll
    for (int i = 0; i < DEPTH; ++i) {
        xr[i] = __builtin_nontemporal_load(pxr + (size_t)i * stride);
        xi[i] = __builtin_nontemporal_load(pxi + (size_t)i * stride);
    }

    #pragma unroll
    for (int t = 0; t < T_STEPS; ++t) {
        const int s = t & (DEPTH - 1);                 // static after unroll
        v4f axr = xr[s];
        v4f axi = xi[s];
        // refill the slot immediately: load for t+DEPTH goes in flight now,
        // consumed DEPTH steps later.
        if (t + DEPTH < T_STEPS) {
            xr[s] = __builtin_nontemporal_load(pxr + (size_t)(t + DEPTH) * stride);
            xi[s] = __builtin_nontemporal_load(pxi + (size_t)(t + DEPTH) * stride);
        }

        v4f o0, o1;
        #pragma unroll
        for (int j = 0; j < 4; ++j) {
            float ir   = SC * axr[j] * co[j];                // old cos
            float dphi = (om[j] - SC * axi[j] * si[j]) * DT; // old sin
            r[j] = r[j] + ((1.f - r[j] * r[j]) * r[j] + ir) * DT;

            float u  = dphi * dphi;
            float sp = fmaf(u, S4, S3);
            sp = fmaf(u, sp, S2);
            sp = fmaf(u, sp, S1);
            sp = fmaf(u, sp, 1.f);
            sp *= dphi;                                      // sin(dphi)
            float cp = fmaf(u, C4, C3);
            cp = fmaf(u, cp, C2);
            cp = fmaf(u, cp, C1);
            cp = fmaf(u, cp, 1.f);                           // cos(dphi)

            float nco = fmaf(co[j], cp, -si[j] * sp);
            float nsi = fmaf(si[j], cp,  co[j] * sp);
            co[j] = nco; si[j] = nsi;

            o0[j] = r[j] * co[j];
            o1[j] = r[j] * si[j];
        }

        size_t off = (size_t)t * stride;
        __builtin_nontemporal_store(o0, po0 + off);
        __builtin_nontemporal_store(o1, po1 + off);
    }
}

extern "C" void kernel_launch(void* const* d_in, const int* in_sizes, int n_in,
                              void* d_out, int out_size, void* d_ws, size_t ws_size,
                              hipStream_t stream) {
    const float* Xr = (const float*)d_in[0];
    const float* Xi = (const float*)d_in[1];
    const float* Om = (const float*)d_in[2];
    float* out = (float*)d_out;

    dim3 block(256);
    dim3 grid(BS * CHV / 256);   // 256 blocks = 65536 threads, 4 chains each
    hopf_scan_kernel<<<grid, block, 0, stream>>>(Xr, Xi, Om, out);
}

// Round 2
// 226.494 us; speedup vs baseline: 1.0493x; 1.0123x over previous
//
#include <hip/hip_runtime.h>

// Hopf oscillator scan.
// X_r, X_i: [bs=8, T=64, d=32, d=32, nk=32] fp32; omegas: [32,32,32].
// Outputs: (r*cos(phi), r*sin(phi)) each [8,64,32,32,32], concatenated.
// 262,144 independent chains over (bs,d,d,nk); T sequential.
//
// R6: occupancy x width midpoint. R4 (1 chain/thread, dword, 4 waves/SIMD)
// = 3.2 TB/s: narrow 256 B/wave transactions. R5 (4 chains/thread, dwordx4,
// 1 wave/SIMD) = ~3.7 TB/s: full-width but a lone wave per SIMD sawtooths its
// outstanding-load count (can't issue while parked at s_waitcnt; vmcnt
// decrements in issue order). R6: 2 chains/thread -> dwordx2 (512 B/wave-inst,
// still in the 8-16 B/lane sweet spot) with 131072 threads = 2 waves/SIMD and
// DEPTH=16 (32 loads, 16 KiB in flight per wave; 128 KiB/CU across 8 waves).
// Trig via small-angle rotation (R3). Full unroll of T=64.

#define T_STEPS 64
#define CHV2    16384         // float2-chains per batch image (32768 / 2)
#define BS      8
#define DEPTH   16            // pipeline depth in t-steps (2 x dwordx2 per step)

typedef float v2f __attribute__((ext_vector_type(2)));

__global__ __launch_bounds__(256)
void hopf_scan_kernel(const float* __restrict__ Xr,
                      const float* __restrict__ Xi,
                      const float* __restrict__ Om,
                      float* __restrict__ out)
{
    const float DT = 0.01f;
    const float SC = 20.0f;
    // sin(x) = x*(1 + u*(S1 + u*(S2 + u*(S3 + u*S4)))), u = x^2
    const float S1 = -1.6666667e-1f, S2 = 8.3333333e-3f,
                S3 = -1.9841270e-4f, S4 = 2.7557319e-6f;
    // cos(x) = 1 + u*(C1 + u*(C2 + u*(C3 + u*C4)))
    const float C1 = -0.5f, C2 = 4.1666667e-2f,
                C3 = -1.3888889e-3f, C4 = 2.4801587e-5f;

    const v2f* __restrict__ vXr = (const v2f*)Xr;
    const v2f* __restrict__ vXi = (const v2f*)Xi;
    const v2f* __restrict__ vOm = (const v2f*)Om;
    v2f* __restrict__ vout      = (v2f*)out;

    int tid = blockIdx.x * blockDim.x + threadIdx.x;   // 0 .. 131071
    int b   = tid >> 14;                               // CHV2 = 16384 vec-chains
    int cv  = tid & (CHV2 - 1);

    v2f om = vOm[cv];

    const size_t stride = CHV2;                        // v2f elements per t
    size_t base = (size_t)(b * T_STEPS) * stride + cv;
    const v2f* pxr = vXr + base;
    const v2f* pxi = vXi + base;
    v2f* po0 = vout + base;
    v2f* po1 = po0 + (size_t)BS * T_STEPS * stride;

    float r[2]  = {1.f, 1.f};
    float co[2] = {1.f, 1.f};
    float si[2] = {0.f, 0.f};                          // phi0 = 0

    // prime: loads for t = 0..DEPTH-1 (32 dwordx2 loads in flight)
    v2f xr[DEPTH], xi[DEPTH];
    #pragma unroll
    for (int i = 0; i < DEPTH; ++i) {
        xr[i] = __builtin_nontemporal_load(pxr + (size_t)i * stride);
        xi[i] = __builtin_nontemporal_load(pxi + (size_t)i * stride);
    }

    #pragma unroll
    for (int t = 0; t < T_STEPS; ++t) {
        const int s = t & (DEPTH - 1);                 // static after unroll
        v2f axr = xr[s];
        v2f axi = xi[s];
        // refill the slot immediately: load for t+DEPTH goes in flight now,
        // consumed DEPTH steps later.
        if (t + DEPTH < T_STEPS) {
            xr[s] = __builtin_nontemporal_load(pxr + (size_t)(t + DEPTH) * stride);
            xi[s] = __builtin_nontemporal_load(pxi + (size_t)(t + DEPTH) * stride);
        }

        v2f o0, o1;
        #pragma unroll
        for (int j = 0; j < 2; ++j) {
            float ir   = SC * axr[j] * co[j];                // old cos
            float dphi = (om[j] - SC * axi[j] * si[j]) * DT; // old sin
            r[j] = r[j] + ((1.f - r[j] * r[j]) * r[j] + ir) * DT;

            float u  = dphi * dphi;
            float sp = fmaf(u, S4, S3);
            sp = fmaf(u, sp, S2);
            sp = fmaf(u, sp, S1);
            sp = fmaf(u, sp, 1.f);
            sp *= dphi;                                      // sin(dphi)
            float cp = fmaf(u, C4, C3);
            cp = fmaf(u, cp, C2);
            cp = fmaf(u, cp, C1);
            cp = fmaf(u, cp, 1.f);                           // cos(dphi)

            float nco = fmaf(co[j], cp, -si[j] * sp);
            float nsi = fmaf(si[j], cp,  co[j] * sp);
            co[j] = nco; si[j] = nsi;

            o0[j] = r[j] * co[j];
            o1[j] = r[j] * si[j];
        }

        size_t off = (size_t)t * stride;
        __builtin_nontemporal_store(o0, po0 + off);
        __builtin_nontemporal_store(o1, po1 + off);
    }
}

extern "C" void kernel_launch(void* const* d_in, const int* in_sizes, int n_in,
                              void* d_out, int out_size, void* d_ws, size_t ws_size,
                              hipStream_t stream) {
    const float* Xr = (const float*)d_in[0];
    const float* Xi = (const float*)d_in[1];
    const float* Om = (const float*)d_in[2];
    float* out = (float*)d_out;

    dim3 block(256);
    dim3 grid(BS * CHV2 / 256);   // 512 blocks = 131072 threads, 2 chains each
    hopf_scan_kernel<<<grid, block, 0, stream>>>(Xr, Xi, Om, out);
}